// Round 1
// baseline (658.882 us; speedup 1.0000x reference)
//
#include <hip/hip_runtime.h>

#define B_    32
#define NV    1556
#define NI    256
#define NT    1812          // NV + NI
#define D_    512
#define IMGD  2048
#define MV    (B_*NV)       // 49792 = 389*128
#define MI    (B_*NI)       // 8192  = 64*128
#define MQ    (B_*NT)       // 57984
#define SCALE_ 0.08838834764831845f   // (512/4)^-0.5

typedef _Float16 half_t;
typedef __attribute__((ext_vector_type(4))) _Float16 half4;
typedef __attribute__((ext_vector_type(8))) _Float16 half8;
typedef __attribute__((ext_vector_type(4))) float floatx4;

// ---------------------------------------------------------------- convert
// fp32 -> f16 for verts, img_f, and the 5 GEMM weight matrices.
__global__ __launch_bounds__(256) void convert_all(
    const float* __restrict__ verts, const float* __restrict__ img,
    const float* __restrict__ w2, const float* __restrict__ w3,
    const float* __restrict__ w4, const float* __restrict__ w5,
    const float* __restrict__ w6,
    half_t* __restrict__ o0, half_t* __restrict__ o1, half_t* __restrict__ o2,
    half_t* __restrict__ o3, half_t* __restrict__ o4, half_t* __restrict__ o5,
    half_t* __restrict__ o6)
{
    const long E0 = (long)MV * D_;      // 25,493,504
    const long E1 = (long)MI * IMGD;    // 16,777,216
    const long E2 = (long)D_ * IMGD;    //  1,048,576
    const long E3 = (long)D_ * D_;      //    262,144
    const long total4 = (E0 + E1 + E2 + 4 * E3) / 4;
    for (long i = blockIdx.x * (long)blockDim.x + threadIdx.x; i < total4;
         i += (long)gridDim.x * blockDim.x) {
        long e = i * 4;
        const float* s; half_t* d;
        if (e < E0)              { s = verts; d = o0; }
        else if ((e -= E0) < E1) { s = img;   d = o1; }
        else if ((e -= E1) < E2) { s = w2;    d = o2; }
        else if ((e -= E2) < E3) { s = w3;    d = o3; }
        else if ((e -= E3) < E3) { s = w4;    d = o4; }
        else if ((e -= E3) < E3) { s = w5;    d = o5; }
        else                     { e -= E3; s = w6; d = o6; }
        float4 x = *(const float4*)(s + e);
        half4 h = { (half_t)x.x, (half_t)x.y, (half_t)x.z, (half_t)x.w };
        *(half4*)(d + e) = h;
    }
}

// ---------------------------------------------------------------- GEMM
// C[M,512] = A[M,K] (row-major f16) @ Bw[512,K]^T (weights already [n,k]) + bias
// MODE 0: store f16 to Ch at row=grow
// MODE 1: q-remap: crow = (grow/TA)*NT + COFF + grow%TA, store f16
// MODE 2: += q residual (addh at remapped row), store f16
// MODE 3: += addf (fp32 verts), store fp32 to Cf
__device__ __forceinline__ void gload16(const void* g, void* l) {
    __builtin_amdgcn_global_load_lds(
        (const __attribute__((address_space(1))) void*)g,
        (__attribute__((address_space(3))) void*)l, 16, 0, 0);
}

template<int MODE, int TA, int COFF>
__global__ __launch_bounds__(256) void gemm_bt(
    const half_t* __restrict__ A, const half_t* __restrict__ Bw,
    const float* __restrict__ bias, int K,
    half_t* __restrict__ Ch, float* __restrict__ Cf,
    const half_t* __restrict__ addh, const float* __restrict__ addf)
{
    __shared__ __align__(16) half_t As[128 * 32];
    __shared__ __align__(16) half_t Bs[128 * 32];
    const int tid  = threadIdx.x;
    const int lane = tid & 63;
    const int wave = tid >> 6;
    const int wr = (wave >> 1) * 64;
    const int wc = (wave & 1) * 64;
    const int bm = blockIdx.x, bn = blockIdx.y;

    floatx4 acc[4][4];
#pragma unroll
    for (int i = 0; i < 4; i++)
#pragma unroll
        for (int j = 0; j < 4; j++) acc[i][j] = (floatx4){0.f, 0.f, 0.f, 0.f};

    const int c0 = tid, c1 = tid + 256;   // 512 16B-chunks per 128x32 tile
    const half_t* ag0 = A  + (size_t)(bm * 128 + (c0 >> 2)) * K + (c0 & 3) * 8;
    const half_t* ag1 = A  + (size_t)(bm * 128 + (c1 >> 2)) * K + (c1 & 3) * 8;
    const half_t* bg0 = Bw + (size_t)(bn * 128 + (c0 >> 2)) * K + (c0 & 3) * 8;
    const half_t* bg1 = Bw + (size_t)(bn * 128 + (c1 >> 2)) * K + (c1 & 3) * 8;
    half_t* al0 = &As[c0 * 8]; half_t* al1 = &As[c1 * 8];
    half_t* bl0 = &Bs[c0 * 8]; half_t* bl1 = &Bs[c1 * 8];

    const int fr = (lane & 15) * 32 + (lane >> 4) * 8;  // fragment offset in tile

    for (int k0 = 0; k0 < K; k0 += 32) {
        __syncthreads();
        gload16(ag0 + k0, al0);
        gload16(ag1 + k0, al1);
        gload16(bg0 + k0, bl0);
        gload16(bg1 + k0, bl1);
        __syncthreads();
        half8 a[4], b[4];
#pragma unroll
        for (int i = 0; i < 4; i++)
            a[i] = *(const half8*)&As[(wr + i * 16) * 32 + fr];
#pragma unroll
        for (int j = 0; j < 4; j++)
            b[j] = *(const half8*)&Bs[(wc + j * 16) * 32 + fr];
#pragma unroll
        for (int i = 0; i < 4; i++)
#pragma unroll
            for (int j = 0; j < 4; j++)
                acc[i][j] = __builtin_amdgcn_mfma_f32_16x16x32_f16(
                    a[i], b[j], acc[i][j], 0, 0, 0);
    }

    const int colbase = bn * 128 + wc + (lane & 15);
    const int rowbase = bm * 128 + wr + ((lane >> 4) << 2);
#pragma unroll
    for (int i = 0; i < 4; i++) {
#pragma unroll
        for (int j = 0; j < 4; j++) {
            const int col = colbase + j * 16;
            const float bv = bias[col];
#pragma unroll
            for (int r = 0; r < 4; r++) {
                const int grow = rowbase + i * 16 + r;
                float v = acc[i][j][r] + bv;
                if (MODE == 0) {
                    Ch[(size_t)grow * D_ + col] = (half_t)v;
                } else if (MODE == 1) {
                    const int b = grow / TA, t = grow - b * TA;
                    Ch[((size_t)b * NT + COFF + t) * D_ + col] = (half_t)v;
                } else if (MODE == 2) {
                    const int b = grow / NV, t = grow - b * NV;
                    v += (float)addh[((size_t)b * NT + t) * D_ + col];
                    Ch[(size_t)grow * D_ + col] = (half_t)v;
                } else {
                    v += addf[(size_t)grow * D_ + col];
                    Cf[(size_t)grow * D_ + col] = v;
                }
            }
        }
    }
}

// ---------------------------------------------------------------- l2norm q + logits
__global__ __launch_bounds__(256) void norm_q(
    half_t* __restrict__ qb, const float* __restrict__ wg, float* __restrict__ araw)
{
    const int row  = blockIdx.x * 4 + (threadIdx.x >> 6);
    const int lane = threadIdx.x & 63;
    half_t* p = qb + (size_t)row * D_ + lane * 8;
    half8 v = *(const half8*)p;
    float f[8]; float ss = 0.f;
#pragma unroll
    for (int r = 0; r < 8; r++) { f[r] = (float)v[r]; ss += f[r] * f[r]; }
#pragma unroll
    for (int off = 32; off > 0; off >>= 1) ss += __shfl_xor(ss, off, 64);
    const float sc = 1.0f / fmaxf(sqrtf(ss), 1e-12f);
    float dot = 0.f;
    half8 o;
#pragma unroll
    for (int r = 0; r < 8; r++) {
        float q = f[r] * sc;
        o[r] = (half_t)q;
        dot += q * wg[lane * 8 + r];
    }
    *(half8*)p = o;
#pragma unroll
    for (int off = 32; off > 0; off >>= 1) dot += __shfl_xor(dot, off, 64);
    if (lane == 0) araw[row] = dot * SCALE_;
}

// ---------------------------------------------------------------- softmax weights (per batch) + zero g
__global__ __launch_bounds__(256) void softmax_w(
    float* __restrict__ araw, float* __restrict__ g)
{
    const int b = blockIdx.x;
    float* a = araw + (size_t)b * NT;
    g[b * D_ + threadIdx.x] = 0.f;
    g[b * D_ + 256 + threadIdx.x] = 0.f;
    __shared__ float red[8];
    const int lane = threadIdx.x & 63, wave = threadIdx.x >> 6;
    float m = -1e30f;
    for (int i = threadIdx.x; i < NT; i += 256) m = fmaxf(m, a[i]);
#pragma unroll
    for (int off = 32; off > 0; off >>= 1) m = fmaxf(m, __shfl_xor(m, off, 64));
    if (lane == 0) red[wave] = m;
    __syncthreads();
    m = fmaxf(fmaxf(red[0], red[1]), fmaxf(red[2], red[3]));
    float s = 0.f;
    for (int i = threadIdx.x; i < NT; i += 256) s += expf(a[i] - m);
#pragma unroll
    for (int off = 32; off > 0; off >>= 1) s += __shfl_xor(s, off, 64);
    if (lane == 0) red[4 + wave] = s;
    __syncthreads();
    s = red[4] + red[5] + red[6] + red[7];
    const float inv = 1.0f / s;
    for (int i = threadIdx.x; i < NT; i += 256) a[i] = expf(a[i] - m) * inv;
}

// ---------------------------------------------------------------- g = sum_n a_n * q_n
__global__ __launch_bounds__(256) void accum_g(
    const float* __restrict__ w, const half_t* __restrict__ qb, float* __restrict__ g)
{
    const int b = blockIdx.y;
    const int t0 = blockIdx.x * 227;
    const int t1 = (t0 + 227 < NT) ? t0 + 227 : NT;
    const int d = threadIdx.x;
    float a0 = 0.f, a1 = 0.f;
    for (int n = t0; n < t1; n++) {
        const float wn = w[(size_t)b * NT + n];
        const half_t* q = qb + ((size_t)b * NT + n) * D_;
        a0 += wn * (float)q[d];
        a1 += wn * (float)q[d + 256];
    }
    atomicAdd(&g[b * D_ + d], a0);
    atomicAdd(&g[b * D_ + d + 256], a1);
}

// ---------------------------------------------------------------- l2norm k, multiply by g
__global__ __launch_bounds__(256) void norm_k(
    half_t* __restrict__ kb, const float* __restrict__ g)
{
    const int row  = blockIdx.x * 4 + (threadIdx.x >> 6);
    const int lane = threadIdx.x & 63;
    const int b = row / NV;
    half_t* p = kb + (size_t)row * D_ + lane * 8;
    half8 v = *(const half8*)p;
    float f[8]; float ss = 0.f;
#pragma unroll
    for (int r = 0; r < 8; r++) { f[r] = (float)v[r]; ss += f[r] * f[r]; }
#pragma unroll
    for (int off = 32; off > 0; off >>= 1) ss += __shfl_xor(ss, off, 64);
    const float sc = 1.0f / fmaxf(sqrtf(ss), 1e-12f);
    const float* gp = g + b * D_ + lane * 8;
    half8 o;
#pragma unroll
    for (int r = 0; r < 8; r++) o[r] = (half_t)(f[r] * sc * gp[r]);
    *(half8*)p = o;
}

// ---------------------------------------------------------------- launch
extern "C" void kernel_launch(void* const* d_in, const int* in_sizes, int n_in,
                              void* d_out, int out_size, void* d_ws, size_t ws_size,
                              hipStream_t stream)
{
    const float* verts  = (const float*)d_in[0];
    const float* imgf   = (const float*)d_in[1];
    const float* fc_w   = (const float*)d_in[2];
    const float* fc_b   = (const float*)d_in[3];
    const float* q_w    = (const float*)d_in[4];
    const float* q_b    = (const float*)d_in[5];
    const float* k_w    = (const float*)d_in[6];
    const float* k_b    = (const float*)d_in[7];
    const float* w_g    = (const float*)d_in[8];
    const float* proj_w = (const float*)d_in[9];
    const float* proj_b = (const float*)d_in[10];
    const float* fin_w  = (const float*)d_in[11];
    const float* fin_b  = (const float*)d_in[12];

    char* ws = (char*)d_ws;
    size_t off = 0;
    auto alloc = [&](size_t bytes) -> void* {
        void* p = ws + off;
        off += (bytes + 255) & ~(size_t)255;
        return p;
    };
    half_t* vb   = (half_t*)alloc((size_t)MV * D_ * 2);
    half_t* ib   = (half_t*)alloc((size_t)MI * IMGD * 2);
    half_t* fcwb = (half_t*)alloc((size_t)D_ * IMGD * 2);
    half_t* qwb  = (half_t*)alloc((size_t)D_ * D_ * 2);
    half_t* kwb  = (half_t*)alloc((size_t)D_ * D_ * 2);
    half_t* pwb  = (half_t*)alloc((size_t)D_ * D_ * 2);
    half_t* fwb  = (half_t*)alloc((size_t)D_ * D_ * 2);
    half_t* imgp = (half_t*)alloc((size_t)MI * D_ * 2);
    half_t* qb   = (half_t*)alloc((size_t)MQ * D_ * 2);
    half_t* kb   = (half_t*)alloc((size_t)MV * D_ * 2);
    half_t* ob   = (half_t*)alloc((size_t)MV * D_ * 2);
    float*  araw = (float*)alloc((size_t)MQ * 4);
    float*  g    = (float*)alloc((size_t)B_ * D_ * 4);

    convert_all<<<4096, 256, 0, stream>>>(verts, imgf, fc_w, q_w, k_w, proj_w, fin_w,
                                          vb, ib, fcwb, qwb, kwb, pwb, fwb);
    // img projection: imgp = img_f @ fc_w^T + fc_b
    gemm_bt<0, 1, 0><<<dim3(MI / 128, 4), 256, 0, stream>>>(
        ib, fcwb, fc_b, IMGD, imgp, nullptr, nullptr, nullptr);
    // q (verts part) -> qb[b*NT + t]
    gemm_bt<1, NV, 0><<<dim3(MV / 128, 4), 256, 0, stream>>>(
        vb, qwb, q_b, D_, qb, nullptr, nullptr, nullptr);
    // q (img part) -> qb[b*NT + NV + t]
    gemm_bt<1, NI, NV><<<dim3(MI / 128, 4), 256, 0, stream>>>(
        imgp, qwb, q_b, D_, qb, nullptr, nullptr, nullptr);
    // normalize q rows, compute logits
    norm_q<<<MQ / 4, 256, 0, stream>>>(qb, w_g, araw);
    // softmax over tokens (per batch), zero g
    softmax_w<<<B_, 256, 0, stream>>>(araw, g);
    // g = sum_n a_n q_n
    accum_g<<<dim3(8, B_), 256, 0, stream>>>(araw, qb, g);
    // k (verts only)
    gemm_bt<0, 1, 0><<<dim3(MV / 128, 4), 256, 0, stream>>>(
        vb, kwb, k_b, D_, kb, nullptr, nullptr, nullptr);
    // normalize k rows, multiply by g
    norm_k<<<MV / 4, 256, 0, stream>>>(kb, g);
    // out1 = (g*k) @ proj_w^T + proj_b + q
    gemm_bt<2, NV, 0><<<dim3(MV / 128, 4), 256, 0, stream>>>(
        kb, pwb, proj_b, D_, ob, nullptr, qb, nullptr);
    // out = out1 @ final_w^T + final_b + verts  (fp32 store)
    gemm_bt<3, 1, 0><<<dim3(MV / 128, 4), 256, 0, stream>>>(
        ob, fwb, fin_b, D_, nullptr, (float*)d_out, nullptr, verts);
}